// Round 5
// baseline (21.408 us; speedup 1.0000x reference)
//
#include <hip/hip_runtime.h>
#include <hip/hip_bf16.h>

#define D 64
#define BU 1024
#define BI 4096
#define L 50

typedef __attribute__((ext_vector_type(4))) float f32x4;
typedef __attribute__((ext_vector_type(8))) short bf16x8;

__device__ __forceinline__ ushort f2bf(float x) {
    union { float f; unsigned u; } v; v.f = x;
    unsigned r = v.u + 0x7fff + ((v.u >> 16) & 1);  // round-to-nearest-even
    return (ushort)(r >> 16);
}

// Prep: blocks [0,1024) = one user each (L split over 4 waves, LDS reduce).
//       blocks [1024,1152) = 32 item rows each, fp32->bf16 + bias gather.
__global__ __launch_bounds__(256) void k_prep(
    const int* __restrict__ user_ids, const int* __restrict__ item_ids,
    const int* __restrict__ fb_idx, const float* __restrict__ fb_val,
    const float* __restrict__ uw, const float* __restrict__ ub,
    const float* __restrict__ iw, const float* __restrict__ ib,
    const float* __restrict__ We,
    ushort* __restrict__ eff, ushort* __restrict__ iwg,
    float* __restrict__ ubg, float* __restrict__ ibg) {
    const int b = blockIdx.x;
    const int t = threadIdx.x;

    if (b < BU) {
        // ---- one user per block; 4 waves split L = 13+13+13+11 ----
        __shared__ float s_part[4][D];
        const int wave = t >> 6;
        const int lane = t & 63;
        const int u = b;
        const int lo = wave * 13;
        float acc = 0.f;
        #pragma unroll
        for (int j = 0; j < 13; ++j) {
            const int l = lo + j;
            if (l < L) {
                const int   ix = fb_idx[u * L + l];
                const float v  = fb_val[u * L + l];
                acc = fmaf(v, We[(size_t)ix * D + lane], acc);
            }
        }
        s_part[wave][lane] = acc;
        __syncthreads();
        if (wave == 0) {
            const int uid = user_ids[u];
            const float r = uw[(size_t)uid * D + lane]
                          + s_part[0][lane] + s_part[1][lane]
                          + s_part[2][lane] + s_part[3][lane];
            eff[u * D + lane] = f2bf(r);
            if (lane == 0) ubg[u] = ub[uid];
        }
    } else {
        // ---- 32 item rows per block; 8 threads/row, 8 floats each ----
        const int base = (b - BU) * 32;
        const int row  = base + (t >> 3);
        const int seg  = (t & 7) * 8;
        const int iid  = item_ids[row];
        const float4 f0 = *(const float4*)(iw + (size_t)iid * D + seg);
        const float4 f1 = *(const float4*)(iw + (size_t)iid * D + seg + 4);
        bf16x8 o;
        o[0] = (short)f2bf(f0.x); o[1] = (short)f2bf(f0.y);
        o[2] = (short)f2bf(f0.z); o[3] = (short)f2bf(f0.w);
        o[4] = (short)f2bf(f1.x); o[5] = (short)f2bf(f1.y);
        o[6] = (short)f2bf(f1.z); o[7] = (short)f2bf(f1.w);
        *(bf16x8*)(iwg + row * D + seg) = o;
        if (t < 32) ibg[base + t] = ib[item_ids[base + t]];
    }
}

// GEMM v2: wave tile 16(M)x32(N), block tile 16x128, grid 32x64 = 2048 blocks
// -> 8 blocks/CU, 8 waves/SIMD for latency hiding. VGPR capped via launch_bounds.
__global__ __launch_bounds__(256, 8) void k_gemm(
    const ushort* __restrict__ eff, const ushort* __restrict__ iwg,
    const float* __restrict__ ubg, const float* __restrict__ ibg,
    const float* __restrict__ bias, float* __restrict__ out) {
    const int lane = threadIdx.x & 63;
    const int wave = threadIdx.x >> 6;
    const int m0 = blockIdx.y * 16;
    const int n0 = blockIdx.x * 128 + wave * 32;
    const int lr = lane & 15;
    const int g  = lane >> 4;

    const bf16x8 a0 = *(const bf16x8*)(eff + (m0 + lr) * D + g * 8);
    const bf16x8 a1 = *(const bf16x8*)(eff + (m0 + lr) * D + 32 + g * 8);

    f32x4 acc[2];
    #pragma unroll
    for (int c = 0; c < 2; ++c) {
        acc[c] = (f32x4){0.f, 0.f, 0.f, 0.f};
        const int col = n0 + c * 16 + lr;
        const bf16x8 b0 = *(const bf16x8*)(iwg + col * D + g * 8);
        const bf16x8 b1 = *(const bf16x8*)(iwg + col * D + 32 + g * 8);
        acc[c] = __builtin_amdgcn_mfma_f32_16x16x32_bf16(a0, b0, acc[c], 0, 0, 0);
        acc[c] = __builtin_amdgcn_mfma_f32_16x16x32_bf16(a1, b1, acc[c], 0, 0, 0);
    }

    const float bb = bias[0];
    float ubr[4];
    #pragma unroll
    for (int r = 0; r < 4; ++r) ubr[r] = ubg[m0 + g * 4 + r];

    #pragma unroll
    for (int c = 0; c < 2; ++c) {
        const int col = n0 + c * 16 + lr;
        const float ibc = ibg[col] + bb;
        #pragma unroll
        for (int r = 0; r < 4; ++r)
            out[(size_t)(m0 + g * 4 + r) * BI + col] = acc[c][r] + ubr[r] + ibc;
    }
}

extern "C" void kernel_launch(void* const* d_in, const int* in_sizes, int n_in,
                              void* d_out, int out_size, void* d_ws, size_t ws_size,
                              hipStream_t stream) {
    const int*   user_ids = (const int*)  d_in[0];
    const int*   item_ids = (const int*)  d_in[1];
    const int*   fb_idx   = (const int*)  d_in[2];
    const float* fb_val   = (const float*)d_in[3];
    const float* uw       = (const float*)d_in[4];
    const float* ub       = (const float*)d_in[5];
    const float* iw       = (const float*)d_in[6];
    const float* ib       = (const float*)d_in[7];
    const float* bias     = (const float*)d_in[8];
    const float* We       = (const float*)d_in[9];

    char* ws = (char*)d_ws;
    ushort* eff = (ushort*)(ws);                         // 1024*64*2   = 131072 B
    ushort* iwg = (ushort*)(ws + 131072);                // 4096*64*2   = 524288 B
    float*  ubg = (float*)(ws + 131072 + 524288);        // 1024*4      = 4096 B
    float*  ibg = (float*)(ws + 131072 + 524288 + 4096); // 4096*4      = 16384 B
    float*  out = (float*)d_out;

    k_prep<<<BU + BI / 32, 256, 0, stream>>>(user_ids, item_ids, fb_idx, fb_val,
                                             uw, ub, iw, ib, We, eff, iwg, ubg, ibg);
    k_gemm<<<dim3(BI / 128, BU / 16), 256, 0, stream>>>(eff, iwg, ubg, ibg, bias, out);
}

// Round 6
// 20.573 us; speedup vs baseline: 1.0406x; 1.0406x over previous
//
#include <hip/hip_runtime.h>
#include <hip/hip_bf16.h>

#define D 64
#define BU 1024
#define BI 4096
#define L 50

typedef __attribute__((ext_vector_type(4))) float f32x4;
typedef __attribute__((ext_vector_type(8))) short bf16x8;

__device__ __forceinline__ ushort f2bf(float x) {
    union { float f; unsigned u; } v; v.f = x;
    unsigned r = v.u + 0x7fff + ((v.u >> 16) & 1);  // round-to-nearest-even
    return (ushort)(r >> 16);
}

// Prep: blocks [0,1024) = one user each (L split over 4 waves, LDS reduce).
//       blocks [1024,1152) = 32 item rows each, fp32->bf16 + bias gather.
__global__ __launch_bounds__(256) void k_prep(
    const int* __restrict__ user_ids, const int* __restrict__ item_ids,
    const int* __restrict__ fb_idx, const float* __restrict__ fb_val,
    const float* __restrict__ uw, const float* __restrict__ ub,
    const float* __restrict__ iw, const float* __restrict__ ib,
    const float* __restrict__ We,
    ushort* __restrict__ eff, ushort* __restrict__ iwg,
    float* __restrict__ ubg, float* __restrict__ ibg) {
    const int b = blockIdx.x;
    const int t = threadIdx.x;

    if (b < BU) {
        // ---- one user per block; 4 waves split L = 13+13+13+11 ----
        __shared__ float s_part[4][D];
        const int wave = t >> 6;
        const int lane = t & 63;
        const int u = b;
        const int lo = wave * 13;
        float acc = 0.f;
        #pragma unroll
        for (int j = 0; j < 13; ++j) {
            const int l = lo + j;
            if (l < L) {
                const int   ix = fb_idx[u * L + l];
                const float v  = fb_val[u * L + l];
                acc = fmaf(v, We[(size_t)ix * D + lane], acc);
            }
        }
        s_part[wave][lane] = acc;
        __syncthreads();
        if (wave == 0) {
            const int uid = user_ids[u];
            const float r = uw[(size_t)uid * D + lane]
                          + s_part[0][lane] + s_part[1][lane]
                          + s_part[2][lane] + s_part[3][lane];
            eff[u * D + lane] = f2bf(r);
            if (lane == 0) ubg[u] = ub[uid];
        }
    } else {
        // ---- 32 item rows per block; 8 threads/row, 8 floats each ----
        const int base = (b - BU) * 32;
        const int row  = base + (t >> 3);
        const int seg  = (t & 7) * 8;
        const int iid  = item_ids[row];
        const float4 f0 = *(const float4*)(iw + (size_t)iid * D + seg);
        const float4 f1 = *(const float4*)(iw + (size_t)iid * D + seg + 4);
        bf16x8 o;
        o[0] = (short)f2bf(f0.x); o[1] = (short)f2bf(f0.y);
        o[2] = (short)f2bf(f0.z); o[3] = (short)f2bf(f0.w);
        o[4] = (short)f2bf(f1.x); o[5] = (short)f2bf(f1.y);
        o[6] = (short)f2bf(f1.z); o[7] = (short)f2bf(f1.w);
        *(bf16x8*)(iwg + row * D + seg) = o;
        if (t < 32) ibg[base + t] = ib[item_ids[base + t]];
    }
}

// GEMM: per-wave 16(M)x64(N) tile via 8x mfma_f32_16x16x32_bf16, K=64.
// grid (16 n, 64 m) x 256 thr = 1024 blocks, 4/CU. (best-known config, R4)
__global__ __launch_bounds__(256) void k_gemm(
    const ushort* __restrict__ eff, const ushort* __restrict__ iwg,
    const float* __restrict__ ubg, const float* __restrict__ ibg,
    const float* __restrict__ bias, float* __restrict__ out) {
    const int lane = threadIdx.x & 63;
    const int wave = threadIdx.x >> 6;
    const int m0 = blockIdx.y * 16;
    const int n0 = blockIdx.x * 256 + wave * 64;
    const int lr = lane & 15;
    const int g  = lane >> 4;

    const bf16x8 a0 = *(const bf16x8*)(eff + (m0 + lr) * D + g * 8);
    const bf16x8 a1 = *(const bf16x8*)(eff + (m0 + lr) * D + 32 + g * 8);

    f32x4 acc[4];
    #pragma unroll
    for (int c = 0; c < 4; ++c) {
        acc[c] = (f32x4){0.f, 0.f, 0.f, 0.f};
        const int col = n0 + c * 16 + lr;
        const bf16x8 b0 = *(const bf16x8*)(iwg + col * D + g * 8);
        const bf16x8 b1 = *(const bf16x8*)(iwg + col * D + 32 + g * 8);
        acc[c] = __builtin_amdgcn_mfma_f32_16x16x32_bf16(a0, b0, acc[c], 0, 0, 0);
        acc[c] = __builtin_amdgcn_mfma_f32_16x16x32_bf16(a1, b1, acc[c], 0, 0, 0);
    }

    const float bb = bias[0];
    float ubr[4];
    #pragma unroll
    for (int r = 0; r < 4; ++r) ubr[r] = ubg[m0 + g * 4 + r];

    #pragma unroll
    for (int c = 0; c < 4; ++c) {
        const int col = n0 + c * 16 + lr;
        const float ibc = ibg[col] + bb;
        #pragma unroll
        for (int r = 0; r < 4; ++r)
            out[(size_t)(m0 + g * 4 + r) * BI + col] = acc[c][r] + ubr[r] + ibc;
    }
}

extern "C" void kernel_launch(void* const* d_in, const int* in_sizes, int n_in,
                              void* d_out, int out_size, void* d_ws, size_t ws_size,
                              hipStream_t stream) {
    const int*   user_ids = (const int*)  d_in[0];
    const int*   item_ids = (const int*)  d_in[1];
    const int*   fb_idx   = (const int*)  d_in[2];
    const float* fb_val   = (const float*)d_in[3];
    const float* uw       = (const float*)d_in[4];
    const float* ub       = (const float*)d_in[5];
    const float* iw       = (const float*)d_in[6];
    const float* ib       = (const float*)d_in[7];
    const float* bias     = (const float*)d_in[8];
    const float* We       = (const float*)d_in[9];

    char* ws = (char*)d_ws;
    ushort* eff = (ushort*)(ws);                         // 1024*64*2   = 131072 B
    ushort* iwg = (ushort*)(ws + 131072);                // 4096*64*2   = 524288 B
    float*  ubg = (float*)(ws + 131072 + 524288);        // 1024*4      = 4096 B
    float*  ibg = (float*)(ws + 131072 + 524288 + 4096); // 4096*4      = 16384 B
    float*  out = (float*)d_out;

    k_prep<<<BU + BI / 32, 256, 0, stream>>>(user_ids, item_ids, fb_idx, fb_val,
                                             uw, ub, iw, ib, We, eff, iwg, ubg, ibg);
    k_gemm<<<dim3(BI / 256, BU / 16), 256, 0, stream>>>(eff, iwg, ubg, ibg, bias, out);
}